// Round 4
// baseline (613.544 us; speedup 1.0000x reference)
//
#include <hip/hip_runtime.h>
#include <math.h>

#define IMG_H 512
#define IMG_W 512
#define KW 11
#define RAD 5
#define T 8                 // output rows per thread
#define NG (IMG_W / 4)      // 128 float4 column-groups per row

#define C1F (0.01f * 0.01f)
#define C2F (0.03f * 0.03f)

__device__ __forceinline__ float ssim_px(float mu1, float mu2, float sp) {
    float m12 = mu1 * mu2;
    float sigma = sp - m12;
    float sq = mu1 * mu1 + mu2 * mu2;
    return ((2.f * m12 + C1F) * (2.f * sigma + C2F)) / ((sq + C1F) * (sq + C2F));
}

// Each thread: 4 cols (one float4 group) x 8 output rows, all in registers.
// Block: 256 threads = 128 col-groups x 2 row-chunks -> 512 wide x 16 rows.
// GUARD=false: interior row-blocks (all 18 input rows in range) -> branch-free
// straight-line body so the scheduler can hoist loads deep ahead (ILP).
// rb = blockIdx.x * rb_scale + rb_off  (interior: +1; edge: *31 -> {0,31}).
template <bool GUARD>
__global__ __launch_bounds__(256, 4)
void ssim_fused_kernel(const float* __restrict__ A, const float* __restrict__ B,
                       float* __restrict__ out, float inv_total,
                       int rb_scale, int rb_off) {
    __shared__ float wpart[4];

    const int tid = threadIdx.x;
    const int g = tid & (NG - 1);        // col-group 0..127
    const int rchunk = tid >> 7;         // 0..1 (wave-uniform)
    const int img = blockIdx.y;
    const int rb = blockIdx.x * rb_scale + rb_off;
    const int ybase = rb * (2 * T) + rchunk * T;   // first output row

    // Gaussian weights (sigma=1.5, K=11) — fp32 recipe matches np bit-exactly
    // (absmax 0.0 rounds 1-3). Pinned to SGPRs (wave-uniform).
    float w[KW];
    {
        float s = 0.f;
#pragma unroll
        for (int i = 0; i < KW; ++i) {
            float d = (float)(i - RAD);
            w[i] = expf(-(d * d) / 4.5f);
            s += w[i];
        }
        float inv = 1.0f / s;
#pragma unroll
        for (int i = 0; i < KW; ++i) {
            w[i] *= inv;
            w[i] = __int_as_float(__builtin_amdgcn_readfirstlane(__float_as_int(w[i])));
        }
    }

    const float* __restrict__ Ai = A + (size_t)img * IMG_H * IMG_W;
    const float* __restrict__ Bi = B + (size_t)img * IMG_H * IMG_W;

    float4 accA[T], accB[T], accP[T];
#pragma unroll
    for (int o = 0; o < T; ++o) {
        accA[o] = make_float4(0.f, 0.f, 0.f, 0.f);
        accB[o] = accA[o];
        accP[o] = accA[o];
    }

    // Walk T + 2*RAD = 18 input rows; h-conv each, scatter into vertical accs.
#pragma unroll
    for (int i = 0; i < T + 2 * RAD; ++i) {
        int gy = ybase + i - RAD;
        bool inrow = true;
        if (GUARD) inrow = (gy >= 0 && gy < IMG_H);  // wave-uniform
        if (inrow) {
            const float* rowA = Ai + (size_t)gy * IMG_W;
            const float* rowB = Bi + (size_t)gy * IMG_W;

            // 5 aligned float4 groups per array: cols 4g-8 .. 4g+11.
            float fa[20], fb[20];
#pragma unroll
            for (int m = 0; m < 5; ++m) {
                int gm = g + m - 2;
                float4 va = make_float4(0.f, 0.f, 0.f, 0.f);
                float4 vb = va;
                if ((unsigned)gm < (unsigned)NG) {   // only lanes 0,1,126,127 mask
                    va = *(const float4*)(rowA + 4 * gm);
                    vb = *(const float4*)(rowB + 4 * gm);
                }
                fa[4 * m] = va.x; fa[4 * m + 1] = va.y; fa[4 * m + 2] = va.z; fa[4 * m + 3] = va.w;
                fb[4 * m] = vb.x; fb[4 * m + 1] = vb.y; fb[4 * m + 2] = vb.z; fb[4 * m + 3] = vb.w;
            }

            // Horizontal 11-tap conv: output col j uses fa[3+j+k], k=0..10.
            float4 hA = make_float4(0.f, 0.f, 0.f, 0.f);
            float4 hB = hA, hP = hA;
#pragma unroll
            for (int k = 0; k < KW; ++k) {
                float wk = w[k];
                hA.x += wk * fa[3 + k];  hA.y += wk * fa[4 + k];
                hA.z += wk * fa[5 + k];  hA.w += wk * fa[6 + k];
                hB.x += wk * fb[3 + k];  hB.y += wk * fb[4 + k];
                hB.z += wk * fb[5 + k];  hB.w += wk * fb[6 + k];
                hP.x += wk * (fa[3 + k] * fb[3 + k]);
                hP.y += wk * (fa[4 + k] * fb[4 + k]);
                hP.z += wk * (fa[5 + k] * fb[5 + k]);
                hP.w += wk * (fa[6 + k] * fb[6 + k]);
            }

            // Vertical scatter: output o gets weight w[i-o] when 0 <= i-o <= 10.
#pragma unroll
            for (int o = 0; o < T; ++o) {
                if (i - o >= 0 && i - o < KW) {
                    float wk = w[i - o];
                    accA[o].x += wk * hA.x; accA[o].y += wk * hA.y;
                    accA[o].z += wk * hA.z; accA[o].w += wk * hA.w;
                    accB[o].x += wk * hB.x; accB[o].y += wk * hB.y;
                    accB[o].z += wk * hB.z; accB[o].w += wk * hB.w;
                    accP[o].x += wk * hP.x; accP[o].y += wk * hP.y;
                    accP[o].z += wk * hP.z; accP[o].w += wk * hP.w;
                }
            }
        }
    }

    // SSIM formula per pixel + per-thread accumulate (32 px/thread).
    float acc = 0.f;
#pragma unroll
    for (int o = 0; o < T; ++o) {
        acc += ssim_px(accA[o].x, accB[o].x, accP[o].x);
        acc += ssim_px(accA[o].y, accB[o].y, accP[o].y);
        acc += ssim_px(accA[o].z, accB[o].z, accP[o].z);
        acc += ssim_px(accA[o].w, accB[o].w, accP[o].w);
    }

    // Reduce: wave shuffle -> LDS -> one atomic per block.
#pragma unroll
    for (int off = 32; off > 0; off >>= 1)
        acc += __shfl_down(acc, off, 64);
    int wid = tid >> 6;
    int lane = tid & 63;
    if (lane == 0) wpart[wid] = acc;
    __syncthreads();
    if (tid == 0) {
        float s = (wpart[0] + wpart[1]) + (wpart[2] + wpart[3]);
        atomicAdd(out, s * inv_total);
    }
}

extern "C" void kernel_launch(void* const* d_in, const int* in_sizes, int n_in,
                              void* d_out, int out_size, void* d_ws, size_t ws_size,
                              hipStream_t stream) {
    const float* A = (const float*)d_in[0];
    const float* B = (const float*)d_in[1];
    float* out = (float*)d_out;

    const int total = in_sizes[0];                 // 32*1*512*512
    const int nimg = total / (IMG_H * IMG_W);      // 32
    const float inv_total = 1.0f / (float)total;

    hipMemsetAsync(d_out, 0, sizeof(float), stream);

    // Interior row-blocks 1..30: branch-free.
    dim3 gridI(30, nimg);
    ssim_fused_kernel<false><<<gridI, 256, 0, stream>>>(A, B, out, inv_total, 1, 1);
    // Edge row-blocks {0, 31}: guarded.
    dim3 gridE(2, nimg);
    ssim_fused_kernel<true><<<gridE, 256, 0, stream>>>(A, B, out, inv_total, 31, 0);
}

// Round 5
// 371.321 us; speedup vs baseline: 1.6523x; 1.6523x over previous
//
#include <hip/hip_runtime.h>
#include <math.h>

#define IMG_H 512
#define IMG_W 512
#define KW 11
#define RAD 5
#define T 8                 // output rows per thread
#define NG (IMG_W / 4)      // 128 float4 column-groups per row

#define C1F (0.01f * 0.01f)
#define C2F (0.03f * 0.03f)

__device__ __forceinline__ float ssim_px(float mu1, float mu2, float sp) {
    float m12 = mu1 * mu2;
    float sigma = sp - m12;
    float sq = mu1 * mu1 + mu2 * mu2;
    return ((2.f * m12 + C1F) * (2.f * sigma + C2F)) / ((sq + C1F) * (sq + C2F));
}

// Each thread: 4 cols (one float4 group) x 8 output rows, all in registers.
// Block: 256 threads = 128 col-groups x 2 row-chunks -> 512 wide x 16 rows.
// GUARD=false: interior row-blocks -> branch-free straight-line body.
// NOTE (round 4): __launch_bounds__(256,4) capped VGPR at 128 < ~165 live ->
// accumulator spill, 1.4 GB scratch traffic, 6.5x regression. Keep (256,2).
template <bool GUARD>
__global__ __launch_bounds__(256, 2)
void ssim_fused_kernel(const float* __restrict__ A, const float* __restrict__ B,
                       float* __restrict__ out, float inv_total,
                       int rb_scale, int rb_off) {
    __shared__ float wpart[4];

    const int tid = threadIdx.x;
    const int g = tid & (NG - 1);        // col-group 0..127
    const int rchunk = tid >> 7;         // 0..1 (wave-uniform)
    const int img = blockIdx.y;
    const int rb = blockIdx.x * rb_scale + rb_off;
    const int ybase = rb * (2 * T) + rchunk * T;   // first output row

    // Gaussian weights (sigma=1.5, K=11) — fp32 recipe matches np bit-exactly
    // (absmax 0.0 rounds 1-4). Pinned to SGPRs (wave-uniform).
    float w[KW];
    {
        float s = 0.f;
#pragma unroll
        for (int i = 0; i < KW; ++i) {
            float d = (float)(i - RAD);
            w[i] = expf(-(d * d) / 4.5f);
            s += w[i];
        }
        float inv = 1.0f / s;
#pragma unroll
        for (int i = 0; i < KW; ++i) {
            w[i] *= inv;
            w[i] = __int_as_float(__builtin_amdgcn_readfirstlane(__float_as_int(w[i])));
        }
    }

    const float* __restrict__ Ai = A + (size_t)img * IMG_H * IMG_W;
    const float* __restrict__ Bi = B + (size_t)img * IMG_H * IMG_W;

    float4 accA[T], accB[T], accP[T];
#pragma unroll
    for (int o = 0; o < T; ++o) {
        accA[o] = make_float4(0.f, 0.f, 0.f, 0.f);
        accB[o] = accA[o];
        accP[o] = accA[o];
    }

    // Walk T + 2*RAD = 18 input rows; h-conv each, scatter into vertical accs.
#pragma unroll
    for (int i = 0; i < T + 2 * RAD; ++i) {
        int gy = ybase + i - RAD;
        bool inrow = true;
        if (GUARD) inrow = (gy >= 0 && gy < IMG_H);  // wave-uniform
        if (inrow) {
            const float* rowA = Ai + (size_t)gy * IMG_W;
            const float* rowB = Bi + (size_t)gy * IMG_W;

            // 5 aligned float4 groups per array: cols 4g-8 .. 4g+11.
            float fa[20], fb[20];
#pragma unroll
            for (int m = 0; m < 5; ++m) {
                int gm = g + m - 2;
                float4 va = make_float4(0.f, 0.f, 0.f, 0.f);
                float4 vb = va;
                if ((unsigned)gm < (unsigned)NG) {   // only lanes 0,1,126,127 mask
                    va = *(const float4*)(rowA + 4 * gm);
                    vb = *(const float4*)(rowB + 4 * gm);
                }
                fa[4 * m] = va.x; fa[4 * m + 1] = va.y; fa[4 * m + 2] = va.z; fa[4 * m + 3] = va.w;
                fb[4 * m] = vb.x; fb[4 * m + 1] = vb.y; fb[4 * m + 2] = vb.z; fb[4 * m + 3] = vb.w;
            }

            // Horizontal 11-tap conv: output col j uses fa[3+j+k], k=0..10.
            float4 hA = make_float4(0.f, 0.f, 0.f, 0.f);
            float4 hB = hA, hP = hA;
#pragma unroll
            for (int k = 0; k < KW; ++k) {
                float wk = w[k];
                hA.x += wk * fa[3 + k];  hA.y += wk * fa[4 + k];
                hA.z += wk * fa[5 + k];  hA.w += wk * fa[6 + k];
                hB.x += wk * fb[3 + k];  hB.y += wk * fb[4 + k];
                hB.z += wk * fb[5 + k];  hB.w += wk * fb[6 + k];
                hP.x += wk * (fa[3 + k] * fb[3 + k]);
                hP.y += wk * (fa[4 + k] * fb[4 + k]);
                hP.z += wk * (fa[5 + k] * fb[5 + k]);
                hP.w += wk * (fa[6 + k] * fb[6 + k]);
            }

            // Vertical scatter: output o gets weight w[i-o] when 0 <= i-o <= 10.
#pragma unroll
            for (int o = 0; o < T; ++o) {
                if (i - o >= 0 && i - o < KW) {
                    float wk = w[i - o];
                    accA[o].x += wk * hA.x; accA[o].y += wk * hA.y;
                    accA[o].z += wk * hA.z; accA[o].w += wk * hA.w;
                    accB[o].x += wk * hB.x; accB[o].y += wk * hB.y;
                    accB[o].z += wk * hB.z; accB[o].w += wk * hB.w;
                    accP[o].x += wk * hP.x; accP[o].y += wk * hP.y;
                    accP[o].z += wk * hP.z; accP[o].w += wk * hP.w;
                }
            }
        }
    }

    // SSIM formula per pixel + per-thread accumulate (32 px/thread).
    float acc = 0.f;
#pragma unroll
    for (int o = 0; o < T; ++o) {
        acc += ssim_px(accA[o].x, accB[o].x, accP[o].x);
        acc += ssim_px(accA[o].y, accB[o].y, accP[o].y);
        acc += ssim_px(accA[o].z, accB[o].z, accP[o].z);
        acc += ssim_px(accA[o].w, accB[o].w, accP[o].w);
    }

    // Reduce: wave shuffle -> LDS -> one atomic per block.
#pragma unroll
    for (int off = 32; off > 0; off >>= 1)
        acc += __shfl_down(acc, off, 64);
    int wid = tid >> 6;
    int lane = tid & 63;
    if (lane == 0) wpart[wid] = acc;
    __syncthreads();
    if (tid == 0) {
        float s = (wpart[0] + wpart[1]) + (wpart[2] + wpart[3]);
        atomicAdd(out, s * inv_total);
    }
}

extern "C" void kernel_launch(void* const* d_in, const int* in_sizes, int n_in,
                              void* d_out, int out_size, void* d_ws, size_t ws_size,
                              hipStream_t stream) {
    const float* A = (const float*)d_in[0];
    const float* B = (const float*)d_in[1];
    float* out = (float*)d_out;

    const int total = in_sizes[0];                 // 32*1*512*512
    const int nimg = total / (IMG_H * IMG_W);      // 32
    const float inv_total = 1.0f / (float)total;

    hipMemsetAsync(d_out, 0, sizeof(float), stream);

    // Interior row-blocks 1..30: branch-free.
    dim3 gridI(30, nimg);
    ssim_fused_kernel<false><<<gridI, 256, 0, stream>>>(A, B, out, inv_total, 1, 1);
    // Edge row-blocks {0, 31}: guarded.
    dim3 gridE(2, nimg);
    ssim_fused_kernel<true><<<gridE, 256, 0, stream>>>(A, B, out, inv_total, 31, 0);
}